// Round 10
// baseline (170.865 us; speedup 1.0000x reference)
//
#include <hip/hip_runtime.h>
#include <hip/hip_bf16.h>

// B=2, M=2048, HID=1024, NH=16, D=64.  No softmax in the reference, so
//   out = ((h Wq^T)(h Wk^T)^T (h Wv^T)) Wo^T
// reassociates twice:  S_{b,h} = K_h^T V_h  (64x64), and
//   out_b = Q_b @ T_b   with  T_b[h*64+d, n] = sum_j S_{b,h}[d,j] Wo[n, h*64+j]
//
// Dtypes: inputs fp32, d_out fp32; internal bf16 with fp32 accumulate
// (rounds 3-9: absmax 3-4 vs threshold 11.68).
//
// Round-10: merge reduce_s into t_kernel (inline 16-chunk fold of Spart while
// staging; 8x redundant reads of the L2-resident 8MB Spart ~= 2us, buys one
// fewer dispatch + gap and deletes S).  Lessons kept: no dense-reduction
// atomics (r6->r7); XOR swizzle + BK=64 (r6); gemm2 BM=64 for 2 blocks/CU
// (r9); never trade high-occupancy FLOPs for low-occupancy FLOPs (r8).
//
// Pipeline:
//   0. prep: h->hb (bf16), Wq|Wk|Wv->wcat (bf16)
//   1. QKVb = hb @ wcat^T        (4096x3072 bf16)            [MFMA GEMM]
//   2. Spart[bh,c] = K^T V partial over 128 rows             [VALU]
//   3. Tt[b][n,k] = (sum_c Spart -> S_h; S_h Wo_h^T)^T       [VALU]
//   4. out = Q @ Tt_b^T          (4096x1024 fp32 -> d_out)   [MFMA GEMM]

typedef unsigned short u16;
typedef unsigned int u32;
typedef __attribute__((ext_vector_type(8))) short bf16x8;
typedef __attribute__((ext_vector_type(4))) float f32x4;

__device__ __forceinline__ void async_copy16(void* lds, const void* g) {
  __builtin_amdgcn_global_load_lds((const __attribute__((address_space(1))) void*)g,
                                   (__attribute__((address_space(3))) void*)lds,
                                   16, 0, 0);
}

__device__ __forceinline__ u16 f2bf(float f) {
  union { __hip_bfloat16 h; u16 u; } c;
  c.h = __float2bfloat16(f);
  return c.u;
}
__device__ __forceinline__ float bflo(u32 w) {
  union { u32 u; float f; } c; c.u = w << 16; return c.f;
}
__device__ __forceinline__ float bfhi(u32 w) {
  union { u32 u; float f; } c; c.u = w & 0xFFFF0000u; return c.f;
}
__device__ __forceinline__ ushort4 cvt4(float4 v) {
  ushort4 o; o.x = f2bf(v.x); o.y = f2bf(v.y); o.z = f2bf(v.z); o.w = f2bf(v.w);
  return o;
}

// ---------------------------------------------------------------- prep ------
// h->hb, Wq|Wk|Wv->wcat (bf16).  Region bounds are multiples of 256 float4s
// -> block-uniform branches.
__global__ __launch_bounds__(256) void prep(const float4* __restrict__ h,
                                            const float4* __restrict__ wq,
                                            const float4* __restrict__ wk,
                                            const float4* __restrict__ wv,
                                            ushort4* __restrict__ hb,
                                            ushort4* __restrict__ wcat) {
  int i = blockIdx.x * 256 + threadIdx.x;  // float4 units
  if (i < 1048576) { hb[i] = cvt4(h[i]); return; }          // h: 4096x1024
  i -= 1048576;
  if (i < 262144) { wcat[i] = cvt4(wq[i]); return; }
  i -= 262144;
  if (i < 262144) { wcat[262144 + i] = cvt4(wk[i]); return; }
  i -= 262144;
  wcat[524288 + i] = cvt4(wv[i]);
}

// ------------------------------------------------------------- NT GEMM ------
// C[m,n] = sum_k A[m*lda+k] * B[n*K+k].  A,B bf16.  BM x BN tile, BK=64,
// 4 waves arranged (BM/64) x (4/(BM/64)); each wave 64 x BN/WC via
// 4 x NI of 16x16x32 MFMA (2 k-halves).  LDS XOR swizzle (r6): LDS(row,g)
// holds global 16-B k-group g ^ (row&7); applied on the global-read side so
// global_load_lds dest stays wave-uniform base + lane*16.
// If B1 != nullptr, row-blocks with m0 >= 2048 use B1 (per-batch T).
template <bool BF16_OUT, int BM, int BN>
__global__ __launch_bounds__(256) void gemm_bt(const u16* __restrict__ A, int lda,
                                               const u16* __restrict__ B0,
                                               const u16* __restrict__ B1,
                                               void* __restrict__ Cv,
                                               int N, int K) {
  constexpr int WR = BM / 64;       // wave rows (2 or 1)
  constexpr int WC = 4 / WR;        // wave cols (2 or 4)
  constexpr int NI = BN / WC / 16;  // 16-col MFMA tiles per wave
  __shared__ u16 Als[BM * 64];
  __shared__ u16 Bls[BN * 64];
  const int t = threadIdx.x;
  const int lane = t & 63;
  const int wave = t >> 6;
  const int wm = (wave / WC) * 64;
  const int wn = (wave % WC) * (BN / WC);
  const int lrow = lane & 15;      // MFMA m/n index
  const int quad = lane >> 4;      // MFMA k-group (16-B units)
  const int m0 = blockIdx.y * BM;
  const int n0 = blockIdx.x * BN;
  const u16* B = (B1 != nullptr && m0 >= 2048) ? B1 : B0;

  // staging: copy c covers rows c*32..c*32+31; thread t -> row c*32+(t>>3),
  // LDS group t&7 holding global group (t&7)^((t>>3)&7).
  const int srow = t >> 3;
  const int scol = (((t & 7) ^ (srow & 7)) * 8);
  const u16* Ag0 = A + (size_t)(m0 + srow) * lda + scol;
  const u16* Bg0 = B + (size_t)(n0 + srow) * K + scol;
  u16* Al0 = Als + t * 8;  // + c*2048 u16 per copy (32 rows)
  u16* Bl0 = Bls + t * 8;

  f32x4 acc[4][NI];
#pragma unroll
  for (int i = 0; i < 4; ++i)
#pragma unroll
    for (int j = 0; j < NI; ++j) acc[i][j] = {0.f, 0.f, 0.f, 0.f};

  for (int k0 = 0; k0 < K; k0 += 64) {
#pragma unroll
    for (int c = 0; c < BM / 32; ++c)
      async_copy16(Al0 + c * 2048, Ag0 + (size_t)(c * 32) * lda + k0);
#pragma unroll
    for (int c = 0; c < BN / 32; ++c)
      async_copy16(Bl0 + c * 2048, Bg0 + (size_t)(c * 32) * K + k0);
    __syncthreads();

#pragma unroll
    for (int half = 0; half < 2; ++half) {
      const int gg = quad + half * 4;  // global k-group within BK=64
      bf16x8 af[4], bfv[NI];
#pragma unroll
      for (int i = 0; i < 4; ++i) {
        const int ra = wm + i * 16 + lrow;
        af[i] = *(const bf16x8*)(Als + ra * 64 + ((gg ^ (ra & 7)) << 3));
      }
#pragma unroll
      for (int i = 0; i < NI; ++i) {
        const int rb = wn + i * 16 + lrow;
        bfv[i] = *(const bf16x8*)(Bls + rb * 64 + ((gg ^ (rb & 7)) << 3));
      }
#pragma unroll
      for (int mi = 0; mi < 4; ++mi)
#pragma unroll
        for (int ni = 0; ni < NI; ++ni)
          acc[mi][ni] = __builtin_amdgcn_mfma_f32_16x16x32_bf16(
              af[mi], bfv[ni], acc[mi][ni], 0, 0, 0);
    }
    __syncthreads();
  }

  // C/D layout (verified m89/m91): col = lane&15, row = (lane>>4)*4 + r
  const int crow0 = m0 + wm + (lane >> 4) * 4;
  const int ccol0 = n0 + wn + (lane & 15);
#pragma unroll
  for (int mi = 0; mi < 4; ++mi)
#pragma unroll
    for (int ni = 0; ni < NI; ++ni) {
      const int col = ccol0 + ni * 16;
#pragma unroll
      for (int r = 0; r < 4; ++r) {
        const size_t idx = (size_t)(crow0 + mi * 16 + r) * N + col;
        if (BF16_OUT) ((u16*)Cv)[idx]   = f2bf(acc[mi][ni][r]);
        else          ((float*)Cv)[idx] = acc[mi][ni][r];
      }
    }
}

// --------------------------------------------- Spart = partial K^T V --------
// QKVb: (4096, 3072) bf16; cols [0,1024)=Q [1024,2048)=K [2048,3072)=V.
// grid (32 bh, 16 chunks of 128 rows); 64-row LDS stages; each block writes
// its private 64x64 partial to Spart[bh*16 + chunk] with plain stores.
__global__ __launch_bounds__(256) void s_kernel(const u16* __restrict__ QKV,
                                                float* __restrict__ Spart) {
  const int bh = blockIdx.x;
  const int b = bh >> 4, hh = bh & 15;
  const int row0 = b * 2048 + blockIdx.y * 128;
  const u16* Kg = QKV + (size_t)row0 * 3072 + 1024 + hh * 64;

  __shared__ float Ks[64][64];
  __shared__ float Vs[64][64];
  const int t = threadIdx.x;
  const int lr = t >> 2;        // 0..63 row within stage
  const int lc = (t & 3) * 16;  // col group (16 cols)
  const int d1 = (t >> 4) * 4;
  const int d2 = (t & 15) * 4;

  float acc[4][4] = {};

  for (int r0 = 0; r0 < 128; r0 += 64) {
    const u16* kp = Kg + (size_t)(r0 + lr) * 3072 + lc;
    const uint4 kw0 = *(const uint4*)kp;
    const uint4 kw1 = *(const uint4*)(kp + 8);
    const uint4 vw0 = *(const uint4*)(kp + 1024);  // V = K + 1024 cols
    const uint4 vw1 = *(const uint4*)(kp + 1032);
    __syncthreads();  // prev-iter readers done
    float* kd = &Ks[lr][lc];
    *(float4*)(kd)      = float4{bflo(kw0.x), bfhi(kw0.x), bflo(kw0.y), bfhi(kw0.y)};
    *(float4*)(kd + 4)  = float4{bflo(kw0.z), bfhi(kw0.z), bflo(kw0.w), bfhi(kw0.w)};
    *(float4*)(kd + 8)  = float4{bflo(kw1.x), bfhi(kw1.x), bflo(kw1.y), bfhi(kw1.y)};
    *(float4*)(kd + 12) = float4{bflo(kw1.z), bfhi(kw1.z), bflo(kw1.w), bfhi(kw1.w)};
    float* vd = &Vs[lr][lc];
    *(float4*)(vd)      = float4{bflo(vw0.x), bfhi(vw0.x), bflo(vw0.y), bfhi(vw0.y)};
    *(float4*)(vd + 4)  = float4{bflo(vw0.z), bfhi(vw0.z), bflo(vw0.w), bfhi(vw0.w)};
    *(float4*)(vd + 8)  = float4{bflo(vw1.x), bfhi(vw1.x), bflo(vw1.y), bfhi(vw1.y)};
    *(float4*)(vd + 12) = float4{bflo(vw1.z), bfhi(vw1.z), bflo(vw1.w), bfhi(vw1.w)};
    __syncthreads();
#pragma unroll
    for (int r = 0; r < 64; ++r) {
      float kv[4], vv[4];
      *(float4*)kv = *(const float4*)&Ks[r][d1];
      *(float4*)vv = *(const float4*)&Vs[r][d2];
#pragma unroll
      for (int i = 0; i < 4; ++i)
#pragma unroll
        for (int j = 0; j < 4; ++j) acc[i][j] += kv[i] * vv[j];
    }
  }
  float* Sp = Spart + ((size_t)bh * 16 + blockIdx.y) * 4096;
#pragma unroll
  for (int i = 0; i < 4; ++i)
    *(float4*)&Sp[(d1 + i) * 64 + d2] =
        float4{acc[i][0], acc[i][1], acc[i][2], acc[i][3]};
}

// ------------------------------------------- Tt = (S_h Wo_h^T)^T ------------
// Inline-reduces S_{b,h} = sum_c Spart[bh,c] while staging (r10: deletes the
// reduce_s dispatch; Spart is L2/L3-resident so the 8x redundant re-read per
// head costs ~2us aggregate).  T_b[h*64+d, n] = sum_j S[d,j] Wo[n, h*64+j];
// stored transposed (row n, col h*64+d) bf16.  grid (8 n-chunks, 16 heads,
// 2 batches).
__global__ __launch_bounds__(256) void t_kernel(const float* __restrict__ Spart,
                                                const float* __restrict__ Wo,
                                                u16* __restrict__ Tt) {
  const int n0 = blockIdx.x * 128;
  const int hh = blockIdx.y;
  const int b  = blockIdx.z;
  __shared__ float Ss[64][68];
  __shared__ float Ws[128][68];
  const int t = threadIdx.x;
  {
    // sum the 16 chunk partials of this head's 64x64 S tile (ascending c:
    // same order as the old reduce_s -> bit-identical output).
    const float* sg = Spart + (size_t)(b * 16 + hh) * 65536 +
                      (t >> 2) * 64 + (t & 3) * 16;
    float4 a0 = {0.f, 0.f, 0.f, 0.f}, a1 = a0, a2 = a0, a3 = a0;
#pragma unroll
    for (int c = 0; c < 16; ++c) {
      const float4* p = (const float4*)(sg + (size_t)c * 4096);
      a0.x += p[0].x; a0.y += p[0].y; a0.z += p[0].z; a0.w += p[0].w;
      a1.x += p[1].x; a1.y += p[1].y; a1.z += p[1].z; a1.w += p[1].w;
      a2.x += p[2].x; a2.y += p[2].y; a2.z += p[2].z; a2.w += p[2].w;
      a3.x += p[3].x; a3.y += p[3].y; a3.z += p[3].z; a3.w += p[3].w;
    }
    float* sd = &Ss[t >> 2][(t & 3) * 16];
    *(float4*)(sd)      = a0;
    *(float4*)(sd + 4)  = a1;
    *(float4*)(sd + 8)  = a2;
    *(float4*)(sd + 12) = a3;
    const float* wg = Wo + (size_t)(n0 + (t >> 1)) * 1024 + hh * 64 + (t & 1) * 32;
    float* wd = &Ws[t >> 1][(t & 1) * 32];
#pragma unroll
    for (int i = 0; i < 8; ++i) *(float4*)(wd + 4 * i) = *(const float4*)(wg + 4 * i);
  }
  __syncthreads();

  const int td = (t >> 4) * 4;  // d = td..td+3
  const int tn = t & 15;        // n = n0 + tn + 16k
  float acc[4][8] = {};
  for (int jj = 0; jj < 64; jj += 4) {
    float4 sv[4], wv[8];
#pragma unroll
    for (int i = 0; i < 4; ++i) sv[i] = *(const float4*)&Ss[td + i][jj];
#pragma unroll
    for (int k = 0; k < 8; ++k) wv[k] = *(const float4*)&Ws[tn + 16 * k][jj];
#pragma unroll
    for (int i = 0; i < 4; ++i)
#pragma unroll
      for (int k = 0; k < 8; ++k)
        acc[i][k] += sv[i].x * wv[k].x + sv[i].y * wv[k].y +
                     sv[i].z * wv[k].z + sv[i].w * wv[k].w;
  }

  u16* tp = Tt + (size_t)b * 1048576;
#pragma unroll
  for (int k = 0; k < 8; ++k) {
    const int n = n0 + tn + 16 * k;
    ushort4 o;
    o.x = f2bf(acc[0][k]); o.y = f2bf(acc[1][k]);
    o.z = f2bf(acc[2][k]); o.w = f2bf(acc[3][k]);
    *(ushort4*)&tp[(size_t)n * 1024 + hh * 64 + td] = o;
  }
}

// ---------------------------------------------------------------------------
extern "C" void kernel_launch(void* const* d_in, const int* in_sizes, int n_in,
                              void* d_out, int out_size, void* d_ws, size_t ws_size,
                              hipStream_t stream) {
  const float* h  = (const float*)d_in[0];  // (4096, 1024) fp32
  // d_in[1] = key_pe: dead branch in reference, unused.
  const float* Wq = (const float*)d_in[2];
  const float* Wk = (const float*)d_in[3];
  const float* Wv = (const float*)d_in[4];
  const float* Wo = (const float*)d_in[5];

  char* ws = (char*)d_ws;
  u16*   hb    = (u16*)(ws);                    // 4096*1024*2 = 8 MiB @ 0
  u16*   wcat  = (u16*)(ws + (8ull  << 20));    // 3072*1024*2 = 6 MiB
  u16*   QKVb  = (u16*)(ws + (16ull << 20));    // 4096*3072*2 = 24 MiB
  u16*   Tt    = (u16*)(ws + (41ull << 20));    // 2*1024*1024*2 = 4 MiB
  float* Spart = (float*)(ws + (48ull << 20));  // 512*64*64*4 = 8 MiB
  // total ws use: 56 MiB (ws_size = 256 MiB)

  prep<<<7168, 256, 0, stream>>>((const float4*)h, (const float4*)Wq,
                                 (const float4*)Wk, (const float4*)Wv,
                                 (ushort4*)hb, (ushort4*)wcat);
  // QKVb = hb @ wcat^T : (4096 x 3072), K=1024, 768 blocks = 3/CU
  gemm_bt<true, 128, 128><<<dim3(24, 32), 256, 0, stream>>>(
      hb, 1024, wcat, nullptr, QKVb, 3072, 1024);
  s_kernel<<<dim3(32, 16), 256, 0, stream>>>(QKVb, Spart);
  t_kernel<<<dim3(8, 16, 2), 256, 0, stream>>>(Spart, Wo, Tt);
  // out = Q @ Tt_b^T : (4096 x 1024), K=1024, BM=64 -> 512 blocks = 2/CU
  gemm_bt<false, 64, 128><<<dim3(8, 64), 256, 0, stream>>>(
      QKVb, 3072, Tt, Tt + 1048576, d_out, 1024, 1024);
}

// Round 11
// 156.835 us; speedup vs baseline: 1.0895x; 1.0895x over previous
//
#include <hip/hip_runtime.h>
#include <hip/hip_bf16.h>

// B=2, M=2048, HID=1024, NH=16, D=64.  No softmax in the reference, so
//   out = ((h Wq^T)(h Wk^T)^T (h Wv^T)) Wo^T
// reassociates twice:  S_{b,h} = K_h^T V_h  (64x64), and
//   out_b = Q_b @ T_b   with  T_b[h*64+d, n] = sum_j S_{b,h}[d,j] Wo[n, h*64+j]
//
// Dtypes: inputs fp32, d_out fp32; internal bf16 with fp32 accumulate
// (rounds 3-10: absmax 3-4 vs threshold 11.68).
//
// Round-11: exact revert to the round-9 structure (best measured, 158.9us).
// r10's reduce_s-into-t_kernel fold regressed +12us: Spart partials live in
// 8 different XCDs' L2s; the 8x redundant fold re-read (64MB) is L3-priced
// (cross-XCD), and sits serially in t_kernel's staging phase.  Lesson: price
// redundant re-reads by XCD locality, not "L2-resident" size.
// Lessons kept: no dense-reduction atomics (r6->r7); XOR swizzle + BK=64
// (r6); gemm2 BM=64 -> 2 blocks/CU (r9); never trade high-occupancy FLOPs
// for low-occupancy FLOPs (r8).
//
// Pipeline:
//   0. prep: h->hb (bf16), Wq|Wk|Wv->wcat (bf16)
//   1. QKVb = hb @ wcat^T        (4096x3072 bf16)            [MFMA GEMM]
//   2. Spart[bh,c] = K^T V partial over 128 rows             [VALU]
//   2b. S = sum_c Spart          (each line read once)       [BW]
//   3. Tt[b][n,k] = (S_h Wo_h^T)^T  (2 x 1024x1024 bf16)     [VALU]
//   4. out = Q @ Tt_b^T          (4096x1024 fp32 -> d_out)   [MFMA GEMM]

typedef unsigned short u16;
typedef unsigned int u32;
typedef __attribute__((ext_vector_type(8))) short bf16x8;
typedef __attribute__((ext_vector_type(4))) float f32x4;

__device__ __forceinline__ void async_copy16(void* lds, const void* g) {
  __builtin_amdgcn_global_load_lds((const __attribute__((address_space(1))) void*)g,
                                   (__attribute__((address_space(3))) void*)lds,
                                   16, 0, 0);
}

__device__ __forceinline__ u16 f2bf(float f) {
  union { __hip_bfloat16 h; u16 u; } c;
  c.h = __float2bfloat16(f);
  return c.u;
}
__device__ __forceinline__ float bflo(u32 w) {
  union { u32 u; float f; } c; c.u = w << 16; return c.f;
}
__device__ __forceinline__ float bfhi(u32 w) {
  union { u32 u; float f; } c; c.u = w & 0xFFFF0000u; return c.f;
}
__device__ __forceinline__ ushort4 cvt4(float4 v) {
  ushort4 o; o.x = f2bf(v.x); o.y = f2bf(v.y); o.z = f2bf(v.z); o.w = f2bf(v.w);
  return o;
}

// ---------------------------------------------------------------- prep ------
// h->hb, Wq|Wk|Wv->wcat (bf16).  Region bounds are multiples of 256 float4s
// -> block-uniform branches.
__global__ __launch_bounds__(256) void prep(const float4* __restrict__ h,
                                            const float4* __restrict__ wq,
                                            const float4* __restrict__ wk,
                                            const float4* __restrict__ wv,
                                            ushort4* __restrict__ hb,
                                            ushort4* __restrict__ wcat) {
  int i = blockIdx.x * 256 + threadIdx.x;  // float4 units
  if (i < 1048576) { hb[i] = cvt4(h[i]); return; }          // h: 4096x1024
  i -= 1048576;
  if (i < 262144) { wcat[i] = cvt4(wq[i]); return; }
  i -= 262144;
  if (i < 262144) { wcat[262144 + i] = cvt4(wk[i]); return; }
  i -= 262144;
  wcat[524288 + i] = cvt4(wv[i]);
}

// ------------------------------------------------------------- NT GEMM ------
// C[m,n] = sum_k A[m*lda+k] * B[n*K+k].  A,B bf16.  BM x BN tile, BK=64,
// 4 waves arranged (BM/64) x (4/(BM/64)); each wave 64 x BN/WC via
// 4 x NI of 16x16x32 MFMA (2 k-halves).  LDS XOR swizzle (r6): LDS(row,g)
// holds global 16-B k-group g ^ (row&7); applied on the global-read side so
// global_load_lds dest stays wave-uniform base + lane*16.
// If B1 != nullptr, row-blocks with m0 >= 2048 use B1 (per-batch T).
template <bool BF16_OUT, int BM, int BN>
__global__ __launch_bounds__(256) void gemm_bt(const u16* __restrict__ A, int lda,
                                               const u16* __restrict__ B0,
                                               const u16* __restrict__ B1,
                                               void* __restrict__ Cv,
                                               int N, int K) {
  constexpr int WR = BM / 64;       // wave rows (2 or 1)
  constexpr int WC = 4 / WR;        // wave cols (2 or 4)
  constexpr int NI = BN / WC / 16;  // 16-col MFMA tiles per wave
  __shared__ u16 Als[BM * 64];
  __shared__ u16 Bls[BN * 64];
  const int t = threadIdx.x;
  const int lane = t & 63;
  const int wave = t >> 6;
  const int wm = (wave / WC) * 64;
  const int wn = (wave % WC) * (BN / WC);
  const int lrow = lane & 15;      // MFMA m/n index
  const int quad = lane >> 4;      // MFMA k-group (16-B units)
  const int m0 = blockIdx.y * BM;
  const int n0 = blockIdx.x * BN;
  const u16* B = (B1 != nullptr && m0 >= 2048) ? B1 : B0;

  // staging: copy c covers rows c*32..c*32+31; thread t -> row c*32+(t>>3),
  // LDS group t&7 holding global group (t&7)^((t>>3)&7).
  const int srow = t >> 3;
  const int scol = (((t & 7) ^ (srow & 7)) * 8);
  const u16* Ag0 = A + (size_t)(m0 + srow) * lda + scol;
  const u16* Bg0 = B + (size_t)(n0 + srow) * K + scol;
  u16* Al0 = Als + t * 8;  // + c*2048 u16 per copy (32 rows)
  u16* Bl0 = Bls + t * 8;

  f32x4 acc[4][NI];
#pragma unroll
  for (int i = 0; i < 4; ++i)
#pragma unroll
    for (int j = 0; j < NI; ++j) acc[i][j] = {0.f, 0.f, 0.f, 0.f};

  for (int k0 = 0; k0 < K; k0 += 64) {
#pragma unroll
    for (int c = 0; c < BM / 32; ++c)
      async_copy16(Al0 + c * 2048, Ag0 + (size_t)(c * 32) * lda + k0);
#pragma unroll
    for (int c = 0; c < BN / 32; ++c)
      async_copy16(Bl0 + c * 2048, Bg0 + (size_t)(c * 32) * K + k0);
    __syncthreads();

#pragma unroll
    for (int half = 0; half < 2; ++half) {
      const int gg = quad + half * 4;  // global k-group within BK=64
      bf16x8 af[4], bfv[NI];
#pragma unroll
      for (int i = 0; i < 4; ++i) {
        const int ra = wm + i * 16 + lrow;
        af[i] = *(const bf16x8*)(Als + ra * 64 + ((gg ^ (ra & 7)) << 3));
      }
#pragma unroll
      for (int i = 0; i < NI; ++i) {
        const int rb = wn + i * 16 + lrow;
        bfv[i] = *(const bf16x8*)(Bls + rb * 64 + ((gg ^ (rb & 7)) << 3));
      }
#pragma unroll
      for (int mi = 0; mi < 4; ++mi)
#pragma unroll
        for (int ni = 0; ni < NI; ++ni)
          acc[mi][ni] = __builtin_amdgcn_mfma_f32_16x16x32_bf16(
              af[mi], bfv[ni], acc[mi][ni], 0, 0, 0);
    }
    __syncthreads();
  }

  // C/D layout (verified m89/m91): col = lane&15, row = (lane>>4)*4 + r
  const int crow0 = m0 + wm + (lane >> 4) * 4;
  const int ccol0 = n0 + wn + (lane & 15);
#pragma unroll
  for (int mi = 0; mi < 4; ++mi)
#pragma unroll
    for (int ni = 0; ni < NI; ++ni) {
      const int col = ccol0 + ni * 16;
#pragma unroll
      for (int r = 0; r < 4; ++r) {
        const size_t idx = (size_t)(crow0 + mi * 16 + r) * N + col;
        if (BF16_OUT) ((u16*)Cv)[idx]   = f2bf(acc[mi][ni][r]);
        else          ((float*)Cv)[idx] = acc[mi][ni][r];
      }
    }
}

// --------------------------------------------- Spart = partial K^T V --------
// QKVb: (4096, 3072) bf16; cols [0,1024)=Q [1024,2048)=K [2048,3072)=V.
// grid (32 bh, 16 chunks of 128 rows); 64-row LDS stages; each block writes
// its private 64x64 partial to Spart[bh*16 + chunk] with plain stores.
__global__ __launch_bounds__(256) void s_kernel(const u16* __restrict__ QKV,
                                                float* __restrict__ Spart) {
  const int bh = blockIdx.x;
  const int b = bh >> 4, hh = bh & 15;
  const int row0 = b * 2048 + blockIdx.y * 128;
  const u16* Kg = QKV + (size_t)row0 * 3072 + 1024 + hh * 64;

  __shared__ float Ks[64][64];
  __shared__ float Vs[64][64];
  const int t = threadIdx.x;
  const int lr = t >> 2;        // 0..63 row within stage
  const int lc = (t & 3) * 16;  // col group (16 cols)
  const int d1 = (t >> 4) * 4;
  const int d2 = (t & 15) * 4;

  float acc[4][4] = {};

  for (int r0 = 0; r0 < 128; r0 += 64) {
    const u16* kp = Kg + (size_t)(r0 + lr) * 3072 + lc;
    const uint4 kw0 = *(const uint4*)kp;
    const uint4 kw1 = *(const uint4*)(kp + 8);
    const uint4 vw0 = *(const uint4*)(kp + 1024);  // V = K + 1024 cols
    const uint4 vw1 = *(const uint4*)(kp + 1032);
    __syncthreads();  // prev-iter readers done
    float* kd = &Ks[lr][lc];
    *(float4*)(kd)      = float4{bflo(kw0.x), bfhi(kw0.x), bflo(kw0.y), bfhi(kw0.y)};
    *(float4*)(kd + 4)  = float4{bflo(kw0.z), bfhi(kw0.z), bflo(kw0.w), bfhi(kw0.w)};
    *(float4*)(kd + 8)  = float4{bflo(kw1.x), bfhi(kw1.x), bflo(kw1.y), bfhi(kw1.y)};
    *(float4*)(kd + 12) = float4{bflo(kw1.z), bfhi(kw1.z), bflo(kw1.w), bfhi(kw1.w)};
    float* vd = &Vs[lr][lc];
    *(float4*)(vd)      = float4{bflo(vw0.x), bfhi(vw0.x), bflo(vw0.y), bfhi(vw0.y)};
    *(float4*)(vd + 4)  = float4{bflo(vw0.z), bfhi(vw0.z), bflo(vw0.w), bfhi(vw0.w)};
    *(float4*)(vd + 8)  = float4{bflo(vw1.x), bfhi(vw1.x), bflo(vw1.y), bfhi(vw1.y)};
    *(float4*)(vd + 12) = float4{bflo(vw1.z), bfhi(vw1.z), bflo(vw1.w), bfhi(vw1.w)};
    __syncthreads();
#pragma unroll
    for (int r = 0; r < 64; ++r) {
      float kv[4], vv[4];
      *(float4*)kv = *(const float4*)&Ks[r][d1];
      *(float4*)vv = *(const float4*)&Vs[r][d2];
#pragma unroll
      for (int i = 0; i < 4; ++i)
#pragma unroll
        for (int j = 0; j < 4; ++j) acc[i][j] += kv[i] * vv[j];
    }
  }
  float* Sp = Spart + ((size_t)bh * 16 + blockIdx.y) * 4096;
#pragma unroll
  for (int i = 0; i < 4; ++i)
    *(float4*)&Sp[(d1 + i) * 64 + d2] =
        float4{acc[i][0], acc[i][1], acc[i][2], acc[i][3]};
}

// ---------------------------------------------------- S = sum_c Spart -------
__global__ __launch_bounds__(256) void reduce_s(const float4* __restrict__ Spart,
                                                float4* __restrict__ S) {
  const int g = blockIdx.x * 256 + threadIdx.x;  // 0..32767
  const int bh = g >> 10, j = g & 1023;
  const float4* p = Spart + (size_t)bh * 16384 + j;  // 16 chunks * 1024 f4
  float4 a = {0.f, 0.f, 0.f, 0.f};
#pragma unroll
  for (int c = 0; c < 16; ++c) {
    const float4 v = p[(size_t)c * 1024];
    a.x += v.x; a.y += v.y; a.z += v.z; a.w += v.w;
  }
  S[g] = a;
}

// ------------------------------------------- Tt = (S_h Wo_h^T)^T ------------
// T_b[h*64+d, n] = sum_j S_{b,h}[d,j] * Wo[n, h*64+j];  stored transposed
// (row n, col h*64+d) bf16.  grid (8 n-chunks, 16 heads, 2 batches).
__global__ __launch_bounds__(256) void t_kernel(const float* __restrict__ S,
                                                const float* __restrict__ Wo,
                                                u16* __restrict__ Tt) {
  const int n0 = blockIdx.x * 128;
  const int hh = blockIdx.y;
  const int b  = blockIdx.z;
  __shared__ float Ss[64][68];
  __shared__ float Ws[128][68];
  const int t = threadIdx.x;
  {
    const float* sg = S + (size_t)(b * 16 + hh) * 4096 + (t >> 2) * 64 + (t & 3) * 16;
    float* sd = &Ss[t >> 2][(t & 3) * 16];
#pragma unroll
    for (int i = 0; i < 4; ++i) *(float4*)(sd + 4 * i) = *(const float4*)(sg + 4 * i);
    const float* wg = Wo + (size_t)(n0 + (t >> 1)) * 1024 + hh * 64 + (t & 1) * 32;
    float* wd = &Ws[t >> 1][(t & 1) * 32];
#pragma unroll
    for (int i = 0; i < 8; ++i) *(float4*)(wd + 4 * i) = *(const float4*)(wg + 4 * i);
  }
  __syncthreads();

  const int td = (t >> 4) * 4;  // d = td..td+3
  const int tn = t & 15;        // n = n0 + tn + 16k
  float acc[4][8] = {};
  for (int jj = 0; jj < 64; jj += 4) {
    float4 sv[4], wv[8];
#pragma unroll
    for (int i = 0; i < 4; ++i) sv[i] = *(const float4*)&Ss[td + i][jj];
#pragma unroll
    for (int k = 0; k < 8; ++k) wv[k] = *(const float4*)&Ws[tn + 16 * k][jj];
#pragma unroll
    for (int i = 0; i < 4; ++i)
#pragma unroll
      for (int k = 0; k < 8; ++k)
        acc[i][k] += sv[i].x * wv[k].x + sv[i].y * wv[k].y +
                     sv[i].z * wv[k].z + sv[i].w * wv[k].w;
  }

  u16* tp = Tt + (size_t)b * 1048576;
#pragma unroll
  for (int k = 0; k < 8; ++k) {
    const int n = n0 + tn + 16 * k;
    ushort4 o;
    o.x = f2bf(acc[0][k]); o.y = f2bf(acc[1][k]);
    o.z = f2bf(acc[2][k]); o.w = f2bf(acc[3][k]);
    *(ushort4*)&tp[(size_t)n * 1024 + hh * 64 + td] = o;
  }
}

// ---------------------------------------------------------------------------
extern "C" void kernel_launch(void* const* d_in, const int* in_sizes, int n_in,
                              void* d_out, int out_size, void* d_ws, size_t ws_size,
                              hipStream_t stream) {
  const float* h  = (const float*)d_in[0];  // (4096, 1024) fp32
  // d_in[1] = key_pe: dead branch in reference, unused.
  const float* Wq = (const float*)d_in[2];
  const float* Wk = (const float*)d_in[3];
  const float* Wv = (const float*)d_in[4];
  const float* Wo = (const float*)d_in[5];

  char* ws = (char*)d_ws;
  u16*   hb    = (u16*)(ws);                    // 4096*1024*2 = 8 MiB @ 0
  u16*   wcat  = (u16*)(ws + (8ull  << 20));    // 3072*1024*2 = 6 MiB
  u16*   QKVb  = (u16*)(ws + (16ull << 20));    // 4096*3072*2 = 24 MiB
  float* S     = (float*)(ws + (40ull << 20));  // 32*64*64*4  = 0.5 MiB
  u16*   Tt    = (u16*)(ws + (41ull << 20));    // 2*1024*1024*2 = 4 MiB
  float* Spart = (float*)(ws + (48ull << 20));  // 512*64*64*4 = 8 MiB
  // total ws use: 56 MiB (ws_size = 256 MiB)

  prep<<<7168, 256, 0, stream>>>((const float4*)h, (const float4*)Wq,
                                 (const float4*)Wk, (const float4*)Wv,
                                 (ushort4*)hb, (ushort4*)wcat);
  // QKVb = hb @ wcat^T : (4096 x 3072), K=1024, 768 blocks = 3/CU
  gemm_bt<true, 128, 128><<<dim3(24, 32), 256, 0, stream>>>(
      hb, 1024, wcat, nullptr, QKVb, 3072, 1024);
  s_kernel<<<dim3(32, 16), 256, 0, stream>>>(QKVb, Spart);
  reduce_s<<<128, 256, 0, stream>>>((const float4*)Spart, (float4*)S);
  t_kernel<<<dim3(8, 16, 2), 256, 0, stream>>>(S, Wo, Tt);
  // out = Q @ Tt_b^T : (4096 x 1024), K=1024, BM=64 -> 512 blocks = 2/CU
  gemm_bt<false, 64, 128><<<dim3(8, 64), 256, 0, stream>>>(
      QKVb, 3072, Tt, Tt + 1048576, d_out, 1024, 1024);
}